// Round 6
// baseline (145.512 us; speedup 1.0000x reference)
//
#include <hip/hip_runtime.h>

#define NPOS 4096
#define NCH  128
#define NTOT (NPOS * NCH)   // 524288
#define NHEAD 4
#define DH    32
#define NSPLIT 4
#define KSPAN (NPOS / NSPLIT)   // 1024 keys per split
#define NTILE (KSPAN / 64)      // 16 tiles per split

typedef __attribute__((ext_vector_type(8))) short short8;   // 8 bf16
typedef __attribute__((ext_vector_type(4))) float floatx4;  // MFMA acc
typedef unsigned short u16;
typedef unsigned int   u32;

__device__ __forceinline__ u16 f2bf(float f) {              // RNE
  u32 u = __float_as_uint(f);
  u += 0x7fffu + ((u >> 16) & 1u);
  return (u16)(u >> 16);
}
__device__ __forceinline__ u32 pack2bf(float a, float b) {
  return (u32)f2bf(a) | ((u32)f2bf(b) << 16);
}
__device__ __forceinline__ u32 pack2bf_fast(float a, float b) {  // round-half-up
  return ((__float_as_uint(a) + 0x8000u) >> 16) |
         ((__float_as_uint(b) + 0x8000u) & 0xffff0000u);
}
__device__ __forceinline__ float bf2f(u16 h) {
  return __uint_as_float(((u32)h) << 16);
}

// ---------------- GN partial sums (512 blocks) + weight bf16 prep ----------------
__global__ __launch_bounds__(256) void gn_prep_k(const float* __restrict__ x,
                                                 float2* __restrict__ partials,
                                                 u32* __restrict__ bounds,
                                                 const float* __restrict__ qw, const float* __restrict__ kw,
                                                 const float* __restrict__ vw, const float* __restrict__ pw,
                                                 u16* __restrict__ wq, u16* __restrict__ wk,
                                                 u16* __restrict__ wv, u16* __restrict__ wp) {
  int i = blockIdx.x * 256 + threadIdx.x;           // 0..131071 float4
  int w = threadIdx.x >> 6, lane = threadIdx.x & 63;
  float4 a = ((const float4*)x)[i];
  float s  = a.x + a.y + a.z + a.w;
  float sq = a.x*a.x + a.y*a.y + a.z*a.z + a.w*a.w;
#pragma unroll
  for (int m = 1; m < 64; m <<= 1) {
    s  += __shfl_xor(s, m);
    sq += __shfl_xor(sq, m);
  }
  __shared__ float red[8];
  if (lane == 0) { red[w] = s; red[4 + w] = sq; }
  __syncthreads();
  if (threadIdx.x == 0)
    partials[blockIdx.x] = make_float2(red[0]+red[1]+red[2]+red[3],
                                       red[4]+red[5]+red[6]+red[7]);
  if (blockIdx.x == 0 && threadIdx.x < 4) bounds[threadIdx.x] = 0;
  if (blockIdx.x < 16) {
    int t = blockIdx.x * 256 + threadIdx.x;         // 0..4095 float4 idx into 128x128
    const float sc = 0.17677669529663687f * 1.4426950408889634f;  // d^-0.5 * log2e
    float4 v = ((const float4*)qw)[t];
    ((uint2*)wq)[t] = make_uint2(pack2bf(v.x*sc, v.y*sc), pack2bf(v.z*sc, v.w*sc));
    v = ((const float4*)kw)[t];
    ((uint2*)wk)[t] = make_uint2(pack2bf(v.x, v.y), pack2bf(v.z, v.w));
    v = ((const float4*)vw)[t];
    ((uint2*)wv)[t] = make_uint2(pack2bf(v.x, v.y), pack2bf(v.z, v.w));
    v = ((const float4*)pw)[t];
    ((uint2*)wp)[t] = make_uint2(pack2bf(v.x, v.y), pack2bf(v.z, v.w));
  }
}

// ---------------- fused GN + QKV GEMM: 12 waves = 3 mats x 4 heads ----------------
// grid 256 x 768. q,k out [h][n][d]; v out [h][d][n]; bounds[h] = max ||k_n||^2.
__global__ __launch_bounds__(768) void qkv_k(const float* __restrict__ x,
    const float* __restrict__ gw, const float* __restrict__ gb,
    const float2* __restrict__ partials,
    const u16* __restrict__ wq, const u16* __restrict__ wk, const u16* __restrict__ wv,
    const float* __restrict__ qb, const float* __restrict__ kb, const float* __restrict__ vb,
    u16* __restrict__ q, u16* __restrict__ k, u16* __restrict__ v, u32* __restrict__ bounds) {
  const int t = threadIdx.x;
  const int w = t >> 6, lane = t & 63;
  const int l16 = lane & 15, quad = lane >> 4;
  const int n0 = blockIdx.x * 16;
  const floatx4 zero = {0.f, 0.f, 0.f, 0.f};

  __shared__ float red[16];
  __shared__ float2 swb[128];
  __shared__ __align__(16) u16 hs[16][136];        // [n-local][c], padded

  if (t < 512) {
    float2 p = partials[t];
    float s = p.x, sq = p.y;
#pragma unroll
    for (int m = 1; m < 64; m <<= 1) {
      s  += __shfl_xor(s, m);
      sq += __shfl_xor(sq, m);
    }
    if (lane == 0) { red[w] = s; red[8 + w] = sq; }
  }
  __syncthreads();
  float mean = (red[0]+red[1]+red[2]+red[3]+red[4]+red[5]+red[6]+red[7]) * (1.0f / NTOT);
  float var  = (red[8]+red[9]+red[10]+red[11]+red[12]+red[13]+red[14]+red[15]) * (1.0f / NTOT)
               - mean * mean;
  float rstd = rsqrtf(var + 1e-5f);
  if (t < 128) {
    float swv = gw[t] * rstd;
    swb[t] = make_float2(swv, gb[t] - mean * swv);
  }
  __syncthreads();
  if (t < 512) {
    int c = t >> 2, seg = t & 3;
    float4 xv = *(const float4*)(x + (size_t)c * NPOS + n0 + seg * 4);
    float2 sb = swb[c];
    int nl = seg * 4;
    hs[nl + 0][c] = f2bf(xv.x * sb.x + sb.y);
    hs[nl + 1][c] = f2bf(xv.y * sb.x + sb.y);
    hs[nl + 2][c] = f2bf(xv.z * sb.x + sb.y);
    hs[nl + 3][c] = f2bf(xv.w * sb.x + sb.y);
  }
  __syncthreads();

  short8 bfr[4];
#pragma unroll
  for (int kk = 0; kk < 4; kk++)
    bfr[kk] = *(const short8*)&hs[l16][kk * 32 + quad * 8];

  const int mat = w >> 2, head = w & 3, ow = head * 32;
  const u16* wm = (mat == 0) ? wq : (mat == 1) ? wk : wv;
  floatx4 a0 = zero, a1 = zero;
  const u16* ap = wm + (size_t)(ow + l16) * NCH + quad * 8;
#pragma unroll
  for (int kk = 0; kk < 4; kk++) {
    a0 = __builtin_amdgcn_mfma_f32_16x16x32_bf16(*(const short8*)(ap + kk*32),          bfr[kk], a0, 0,0,0);
    a1 = __builtin_amdgcn_mfma_f32_16x16x32_bf16(*(const short8*)(ap + 16*NCH + kk*32), bfr[kk], a1, 0,0,0);
  }
  const int n = n0 + l16;
  if (mat == 0) {
    const float sc = 0.17677669529663687f * 1.4426950408889634f;
    u16* qp = q + (size_t)(head * NPOS + n) * DH;
#pragma unroll
    for (int ss = 0; ss < 2; ss++) {
      floatx4 acc = ss ? a1 : a0;
      int od = ss * 16 + quad * 4;
      float r0 = acc[0] + qb[ow+od+0]*sc, r1 = acc[1] + qb[ow+od+1]*sc;
      float r2 = acc[2] + qb[ow+od+2]*sc, r3 = acc[3] + qb[ow+od+3]*sc;
      *(uint2*)(qp + od) = make_uint2(pack2bf(r0, r1), pack2bf(r2, r3));
    }
  } else if (mat == 1) {
    float sumsq = 0.f;
    u16* kp = k + (size_t)(head * NPOS + n) * DH;
#pragma unroll
    for (int ss = 0; ss < 2; ss++) {
      floatx4 acc = ss ? a1 : a0;
      int od = ss * 16 + quad * 4;
      float r0 = acc[0] + kb[ow+od+0], r1 = acc[1] + kb[ow+od+1];
      float r2 = acc[2] + kb[ow+od+2], r3 = acc[3] + kb[ow+od+3];
      sumsq += r0*r0 + r1*r1 + r2*r2 + r3*r3;
      *(uint2*)(kp + od) = make_uint2(pack2bf(r0, r1), pack2bf(r2, r3));
    }
    sumsq += __shfl_xor(sumsq, 16);
    sumsq += __shfl_xor(sumsq, 32);
#pragma unroll
    for (int m = 1; m < 16; m <<= 1) sumsq = fmaxf(sumsq, __shfl_xor(sumsq, m));
    if (lane == 0) atomicMax(&bounds[head], __float_as_uint(sumsq));
  } else {
    u16* vp = v + (size_t)(head * DH) * NPOS + n;
#pragma unroll
    for (int ss = 0; ss < 2; ss++) {
      floatx4 acc = ss ? a1 : a0;
      int od = ss * 16 + quad * 4;
#pragma unroll
      for (int r = 0; r < 4; r++)
        vp[(size_t)(od + r) * NPOS] = f2bf(acc[r] + vb[ow + od + r]);
    }
  }
}

// ---------------- flash attention: LDS-free via key-permuted S^T ----------------
// grid 1024 x 256: block b -> (split s = b>>8, qtile = b&255); wave w = head.
// K A-frag rows permuted so each lane's S^T C-regs are exactly its PV A-frag:
// pi(s, m) = 32*(s>>1) + (m>>2)*8 + (s&1)*4 + (m&3).
__global__ __launch_bounds__(256) void attn_k(const u16* __restrict__ q, const u16* __restrict__ k,
                                              const u16* __restrict__ v, const u32* __restrict__ bounds,
                                              u32* __restrict__ Opair, float* __restrict__ lpart) {
  const int w = threadIdx.x >> 6, lane = threadIdx.x & 63;
  const int l16 = lane & 15, quad = lane >> 4;
  const int s = blockIdx.x >> 8;
  const int q0 = (blockIdx.x & 255) * 16;
  const int head = w;

  short8 bq = *(const short8*)(q + (size_t)(head * NPOS + q0 + l16) * DH + quad * 8);
  float qn2 = 0.f;
#pragma unroll
  for (int j = 0; j < 8; j++) { float f = bf2f((u16)bq[j]); qn2 += f * f; }
  qn2 += __shfl_xor(qn2, 16);
  qn2 += __shfl_xor(qn2, 32);
  float kmax = sqrtf(__uint_as_float(bounds[head])) * 1.0005f;
  float bound = sqrtf(qn2) * kmax;

  floatx4 o0 = {0,0,0,0}, o1 = {0,0,0,0}, ol = {0,0,0,0};
  short8 ones;
#pragma unroll
  for (int j = 0; j < 8; j++) ones[j] = (short)0x3F80;   // bf16 1.0

  // permuted K row offsets (keys within 64-tile), constant across tiles
  int ko[4];
#pragma unroll
  for (int s2 = 0; s2 < 4; s2++)
    ko[s2] = 32 * (s2 >> 1) + (l16 >> 2) * 8 + (s2 & 1) * 4 + (l16 & 3);

  const u16* kbp = k + (size_t)head * NPOS * DH + quad * 8;
  const u16* vb0 = v + (size_t)(head * DH + l16) * NPOS + quad * 8;
  const u16* vb1 = vb0 + (size_t)16 * NPOS;
  const floatx4 zero = {0,0,0,0};

  int m0 = s * KSPAN;
  short8 ak[4], av[4];
#pragma unroll
  for (int s2 = 0; s2 < 4; s2++)
    ak[s2] = *(const short8*)(kbp + (size_t)(m0 + ko[s2]) * DH);
#pragma unroll
  for (int kc = 0; kc < 2; kc++) {
    av[2*kc]   = *(const short8*)(vb0 + m0 + kc * 32);
    av[2*kc+1] = *(const short8*)(vb1 + m0 + kc * 32);
  }

  for (int it = 0; it < NTILE; it++) {
    const int mn = m0 + 64;
    const bool more = (it + 1 < NTILE);
    short8 nak[4], nav[4];
    if (more) {                                      // prefetch tile it+1
#pragma unroll
      for (int s2 = 0; s2 < 4; s2++)
        nak[s2] = *(const short8*)(kbp + (size_t)(mn + ko[s2]) * DH);
#pragma unroll
      for (int kc = 0; kc < 2; kc++) {
        nav[2*kc]   = *(const short8*)(vb0 + mn + kc * 32);
        nav[2*kc+1] = *(const short8*)(vb1 + mn + kc * 32);
      }
    }
    floatx4 c[4];
#pragma unroll
    for (int s2 = 0; s2 < 4; s2++)
      c[s2] = __builtin_amdgcn_mfma_f32_16x16x32_bf16(ak[s2], bq, zero, 0, 0, 0);
    // exp + pack: lane's own regs ARE its PV A-frags (via pi permutation)
#pragma unroll
    for (int kc = 0; kc < 2; kc++) {
      float pa0 = __builtin_amdgcn_exp2f(c[2*kc][0] - bound);
      float pa1 = __builtin_amdgcn_exp2f(c[2*kc][1] - bound);
      float pa2 = __builtin_amdgcn_exp2f(c[2*kc][2] - bound);
      float pa3 = __builtin_amdgcn_exp2f(c[2*kc][3] - bound);
      float pb0 = __builtin_amdgcn_exp2f(c[2*kc+1][0] - bound);
      float pb1 = __builtin_amdgcn_exp2f(c[2*kc+1][1] - bound);
      float pb2 = __builtin_amdgcn_exp2f(c[2*kc+1][2] - bound);
      float pb3 = __builtin_amdgcn_exp2f(c[2*kc+1][3] - bound);
      uint4 uu = make_uint4(pack2bf_fast(pa0, pa1), pack2bf_fast(pa2, pa3),
                            pack2bf_fast(pb0, pb1), pack2bf_fast(pb2, pb3));
      short8 pa = *(short8*)&uu;
      o0 = __builtin_amdgcn_mfma_f32_16x16x32_bf16(pa, av[2*kc],   o0, 0, 0, 0);
      o1 = __builtin_amdgcn_mfma_f32_16x16x32_bf16(pa, av[2*kc+1], o1, 0, 0, 0);
      ol = __builtin_amdgcn_mfma_f32_16x16x32_bf16(pa, ones,       ol, 0, 0, 0);
    }
    if (more) {
#pragma unroll
      for (int j = 0; j < 4; j++) { ak[j] = nak[j]; av[j] = nav[j]; }
    }
    m0 = mn;
  }

  u32*   op = Opair + (size_t)(s * NHEAD + head) * NPOS * 16;
  float* lp = lpart + (size_t)(s * NHEAD + head) * NPOS;
#pragma unroll
  for (int r = 0; r < 4; r++) {
    int qq = q0 + quad * 4 + r;
    op[(size_t)qq * 16 + l16] = pack2bf(o0[r], o1[r]);
    if (l16 == 0) lp[qq] = ol[r];
  }
}

// ---------------- proj GEMM: LDS-deduped split combine, 8 waves ----------------
// grid 256 x 512; wave w: out rows w*16..w*16+15.
__global__ __launch_bounds__(512) void proj_k(const u32* __restrict__ Opair,
                                              const float* __restrict__ lpart,
                                              const u16* __restrict__ wp,
                                              const float* __restrict__ pb,
                                              const float* __restrict__ x,
                                              float* __restrict__ out) {
  const int t = threadIdx.x;
  const int w = t >> 6, lane = t & 63;
  const int l16 = lane & 15, quad = lane >> 4;
  const int n0 = blockIdx.x * 16;
  const floatx4 zero = {0.f, 0.f, 0.f, 0.f};
  __shared__ __align__(16) u16 at_lds[16][136];

  {                                                  // cooperative combine: 512 thr x 4 ch
    const int n = t & 15, ci = t >> 4;               // ci 0..31
    const int c0 = ci * 4, head = c0 >> 5, off = c0 & 31;
    const int half = off >> 4, j0 = off & 15;
    float acc[4] = {0.f, 0.f, 0.f, 0.f};
    float l = 0.f;
#pragma unroll
    for (int s2 = 0; s2 < NSPLIT; s2++) {
      const u32* pp = Opair + ((size_t)(s2 * NHEAD + head) * NPOS + n0 + n) * 16 + j0;
      uint4 u = *(const uint4*)pp;
      u32 uu[4] = {u.x, u.y, u.z, u.w};
#pragma unroll
      for (int j = 0; j < 4; j++)
        acc[j] += half ? __uint_as_float(uu[j] & 0xffff0000u)
                       : __uint_as_float(uu[j] << 16);
      l += lpart[(size_t)(s2 * NHEAD + head) * NPOS + n0 + n];
    }
    float inv = 1.0f / fmaxf(l, 1e-30f);
    *(uint2*)&at_lds[n][c0] = make_uint2(pack2bf(acc[0]*inv, acc[1]*inv),
                                         pack2bf(acc[2]*inv, acc[3]*inv));
  }
  __syncthreads();

  short8 bfr[4];
#pragma unroll
  for (int kk = 0; kk < 4; kk++)
    bfr[kk] = *(const short8*)&at_lds[l16][kk * 32 + quad * 8];
  const int ow = w * 16;
  floatx4 a0 = zero;
  const u16* ap = wp + (size_t)(ow + l16) * NCH + quad * 8;
#pragma unroll
  for (int kk = 0; kk < 4; kk++)
    a0 = __builtin_amdgcn_mfma_f32_16x16x32_bf16(*(const short8*)(ap + kk*32), bfr[kk], a0, 0,0,0);
  const int n = n0 + l16;
#pragma unroll
  for (int r = 0; r < 4; r++) {
    int o = ow + quad * 4 + r;
    size_t idx = (size_t)o * NPOS + n;
    out[idx] = a0[r] + pb[o] + x[idx];
  }
}

extern "C" void kernel_launch(void* const* d_in, const int* in_sizes, int n_in,
                              void* d_out, int out_size, void* d_ws, size_t ws_size,
                              hipStream_t stream) {
  const float* x   = (const float*)d_in[0];
  const float* gnw = (const float*)d_in[1];
  const float* gnb = (const float*)d_in[2];
  const float* qw  = (const float*)d_in[3];
  const float* qb  = (const float*)d_in[4];
  const float* kw  = (const float*)d_in[5];
  const float* kb  = (const float*)d_in[6];
  const float* vw  = (const float*)d_in[7];
  const float* vb  = (const float*)d_in[8];
  const float* pw  = (const float*)d_in[9];
  const float* pb  = (const float*)d_in[10];
  float* out = (float*)d_out;

  char* wsb = (char*)d_ws;
  float2* partials = (float2*)wsb;                       // 512 x 8 B = 4 KB
  u32*    bounds   = (u32*)(wsb + 4096);                 // 16 B
  u16* wqb = (u16*)(wsb + 8192);                         // 4 x 32 KB
  u16* wkb = wqb + 16384;
  u16* wvb = wkb + 16384;
  u16* wpb = wvb + 16384;
  u16* qbuf = wpb + 16384;                               // [h][n][d] 1 MB
  u16* kbuf = qbuf + NTOT;                               // [h][n][d] 1 MB
  u16* vbuf = kbuf + NTOT;                               // [h][d][n] 1 MB
  u32* Opair = (u32*)(vbuf + NTOT);                      // [4][h][q][16] u32 = 4 MB
  float* lpart = (float*)(Opair + (size_t)NSPLIT * NHEAD * NPOS * 16);  // 256 KB

  gn_prep_k<<<512, 256, 0, stream>>>(x, partials, bounds, qw, kw, vw, pw,
                                     wqb, wkb, wvb, wpb);
  qkv_k<<<256, 768, 0, stream>>>(x, gnw, gnb, partials, wqb, wkb, wvb,
                                 qb, kb, vb, qbuf, kbuf, vbuf, bounds);
  attn_k<<<256 * NSPLIT, 256, 0, stream>>>(qbuf, kbuf, vbuf, bounds, Opair, lpart);
  proj_k<<<256, 512, 0, stream>>>(Opair, lpart, wpb, pb, x, out);
}

// Round 7
// 117.795 us; speedup vs baseline: 1.2353x; 1.2353x over previous
//
#include <hip/hip_runtime.h>

#define NPOS 4096
#define NCH  128
#define NTOT (NPOS * NCH)   // 524288
#define NHEAD 4
#define DH    32
#define NSPLIT 8
#define KSPAN (NPOS / NSPLIT)   // 512 keys per split
#define NTILE (KSPAN / 64)      // 8 tiles per split

typedef __attribute__((ext_vector_type(8))) short short8;   // 8 bf16
typedef __attribute__((ext_vector_type(4))) float floatx4;  // MFMA acc
typedef unsigned short u16;
typedef unsigned int   u32;

__device__ __forceinline__ u16 f2bf(float f) {              // RNE
  u32 u = __float_as_uint(f);
  u += 0x7fffu + ((u >> 16) & 1u);
  return (u16)(u >> 16);
}
__device__ __forceinline__ u32 pack2bf(float a, float b) {
  return (u32)f2bf(a) | ((u32)f2bf(b) << 16);
}
__device__ __forceinline__ u32 pack2bf_fast(float a, float b) {  // round-half-up
  return ((__float_as_uint(a) + 0x8000u) >> 16) |
         ((__float_as_uint(b) + 0x8000u) & 0xffff0000u);
}
__device__ __forceinline__ float bf2f(u16 h) {
  return __uint_as_float(((u32)h) << 16);
}

// ---------------- GN partial sums (512 blocks) + weight bf16 prep ----------------
__global__ __launch_bounds__(256) void gn_prep_k(const float* __restrict__ x,
                                                 float2* __restrict__ partials,
                                                 u32* __restrict__ bounds,
                                                 const float* __restrict__ qw, const float* __restrict__ kw,
                                                 const float* __restrict__ vw, const float* __restrict__ pw,
                                                 u16* __restrict__ wq, u16* __restrict__ wk,
                                                 u16* __restrict__ wv, u16* __restrict__ wp) {
  int i = blockIdx.x * 256 + threadIdx.x;           // 0..131071 float4
  int w = threadIdx.x >> 6, lane = threadIdx.x & 63;
  float4 a = ((const float4*)x)[i];
  float s  = a.x + a.y + a.z + a.w;
  float sq = a.x*a.x + a.y*a.y + a.z*a.z + a.w*a.w;
#pragma unroll
  for (int m = 1; m < 64; m <<= 1) {
    s  += __shfl_xor(s, m);
    sq += __shfl_xor(sq, m);
  }
  __shared__ float red[8];
  if (lane == 0) { red[w] = s; red[4 + w] = sq; }
  __syncthreads();
  if (threadIdx.x == 0)
    partials[blockIdx.x] = make_float2(red[0]+red[1]+red[2]+red[3],
                                       red[4]+red[5]+red[6]+red[7]);
  if (blockIdx.x == 0 && threadIdx.x < 4) bounds[threadIdx.x] = 0;
  if (blockIdx.x < 16) {
    int t = blockIdx.x * 256 + threadIdx.x;         // 0..4095 float4 idx into 128x128
    const float sc = 0.17677669529663687f * 1.4426950408889634f;  // d^-0.5 * log2e
    float4 v = ((const float4*)qw)[t];
    ((uint2*)wq)[t] = make_uint2(pack2bf(v.x*sc, v.y*sc), pack2bf(v.z*sc, v.w*sc));
    v = ((const float4*)kw)[t];
    ((uint2*)wk)[t] = make_uint2(pack2bf(v.x, v.y), pack2bf(v.z, v.w));
    v = ((const float4*)vw)[t];
    ((uint2*)wv)[t] = make_uint2(pack2bf(v.x, v.y), pack2bf(v.z, v.w));
    v = ((const float4*)pw)[t];
    ((uint2*)wp)[t] = make_uint2(pack2bf(v.x, v.y), pack2bf(v.z, v.w));
  }
}

// ---------------- fused GN + QKV GEMM: 12 waves = 3 mats x 4 heads ----------------
__global__ __launch_bounds__(768) void qkv_k(const float* __restrict__ x,
    const float* __restrict__ gw, const float* __restrict__ gb,
    const float2* __restrict__ partials,
    const u16* __restrict__ wq, const u16* __restrict__ wk, const u16* __restrict__ wv,
    const float* __restrict__ qb, const float* __restrict__ kb, const float* __restrict__ vb,
    u16* __restrict__ q, u16* __restrict__ k, u16* __restrict__ v, u32* __restrict__ bounds) {
  const int t = threadIdx.x;
  const int w = t >> 6, lane = t & 63;
  const int l16 = lane & 15, quad = lane >> 4;
  const int n0 = blockIdx.x * 16;
  const floatx4 zero = {0.f, 0.f, 0.f, 0.f};

  __shared__ float red[16];
  __shared__ float2 swb[128];
  __shared__ __align__(16) u16 hs[16][136];

  if (t < 512) {
    float2 p = partials[t];
    float s = p.x, sq = p.y;
#pragma unroll
    for (int m = 1; m < 64; m <<= 1) {
      s  += __shfl_xor(s, m);
      sq += __shfl_xor(sq, m);
    }
    if (lane == 0) { red[w] = s; red[8 + w] = sq; }
  }
  __syncthreads();
  float mean = (red[0]+red[1]+red[2]+red[3]+red[4]+red[5]+red[6]+red[7]) * (1.0f / NTOT);
  float var  = (red[8]+red[9]+red[10]+red[11]+red[12]+red[13]+red[14]+red[15]) * (1.0f / NTOT)
               - mean * mean;
  float rstd = rsqrtf(var + 1e-5f);
  if (t < 128) {
    float swv = gw[t] * rstd;
    swb[t] = make_float2(swv, gb[t] - mean * swv);
  }
  __syncthreads();
  if (t < 512) {
    int c = t >> 2, seg = t & 3;
    float4 xv = *(const float4*)(x + (size_t)c * NPOS + n0 + seg * 4);
    float2 sb = swb[c];
    int nl = seg * 4;
    hs[nl + 0][c] = f2bf(xv.x * sb.x + sb.y);
    hs[nl + 1][c] = f2bf(xv.y * sb.x + sb.y);
    hs[nl + 2][c] = f2bf(xv.z * sb.x + sb.y);
    hs[nl + 3][c] = f2bf(xv.w * sb.x + sb.y);
  }
  __syncthreads();

  short8 bfr[4];
#pragma unroll
  for (int kk = 0; kk < 4; kk++)
    bfr[kk] = *(const short8*)&hs[l16][kk * 32 + quad * 8];

  const int mat = w >> 2, head = w & 3, ow = head * 32;
  const u16* wm = (mat == 0) ? wq : (mat == 1) ? wk : wv;
  floatx4 a0 = zero, a1 = zero;
  const u16* ap = wm + (size_t)(ow + l16) * NCH + quad * 8;
#pragma unroll
  for (int kk = 0; kk < 4; kk++) {
    a0 = __builtin_amdgcn_mfma_f32_16x16x32_bf16(*(const short8*)(ap + kk*32),          bfr[kk], a0, 0,0,0);
    a1 = __builtin_amdgcn_mfma_f32_16x16x32_bf16(*(const short8*)(ap + 16*NCH + kk*32), bfr[kk], a1, 0,0,0);
  }
  const int n = n0 + l16;
  if (mat == 0) {
    const float sc = 0.17677669529663687f * 1.4426950408889634f;
    u16* qp = q + (size_t)(head * NPOS + n) * DH;
#pragma unroll
    for (int ss = 0; ss < 2; ss++) {
      floatx4 acc = ss ? a1 : a0;
      int od = ss * 16 + quad * 4;
      float r0 = acc[0] + qb[ow+od+0]*sc, r1 = acc[1] + qb[ow+od+1]*sc;
      float r2 = acc[2] + qb[ow+od+2]*sc, r3 = acc[3] + qb[ow+od+3]*sc;
      *(uint2*)(qp + od) = make_uint2(pack2bf(r0, r1), pack2bf(r2, r3));
    }
  } else if (mat == 1) {
    float sumsq = 0.f;
    u16* kp = k + (size_t)(head * NPOS + n) * DH;
#pragma unroll
    for (int ss = 0; ss < 2; ss++) {
      floatx4 acc = ss ? a1 : a0;
      int od = ss * 16 + quad * 4;
      float r0 = acc[0] + kb[ow+od+0], r1 = acc[1] + kb[ow+od+1];
      float r2 = acc[2] + kb[ow+od+2], r3 = acc[3] + kb[ow+od+3];
      sumsq += r0*r0 + r1*r1 + r2*r2 + r3*r3;
      *(uint2*)(kp + od) = make_uint2(pack2bf(r0, r1), pack2bf(r2, r3));
    }
    sumsq += __shfl_xor(sumsq, 16);
    sumsq += __shfl_xor(sumsq, 32);
#pragma unroll
    for (int m = 1; m < 16; m <<= 1) sumsq = fmaxf(sumsq, __shfl_xor(sumsq, m));
    if (lane == 0) atomicMax(&bounds[head], __float_as_uint(sumsq));
  } else {
    u16* vp = v + (size_t)(head * DH) * NPOS + n;
#pragma unroll
    for (int ss = 0; ss < 2; ss++) {
      floatx4 acc = ss ? a1 : a0;
      int od = ss * 16 + quad * 4;
#pragma unroll
      for (int r = 0; r < 4; r++)
        vp[(size_t)(od + r) * NPOS] = f2bf(acc[r] + vb[ow + od + r]);
    }
  }
}

// ---------------- flash attention: Q=64/wave, LDS-free, 8-way split-K ----------------
// grid 512 x 256: block b -> (split s = b>>6, qtile = b&63, 64 queries); wave = head.
// K A-frag permutation pi(s2,m) makes each lane's S^T C-regs its PV A-frag.
// -bound folded into the QK MFMA C operand.
__global__ __launch_bounds__(256, 2) void attn_k(const u16* __restrict__ q, const u16* __restrict__ k,
                                                 const u16* __restrict__ v, const u32* __restrict__ bounds,
                                                 u32* __restrict__ Opair, float* __restrict__ lpart) {
  const int w = threadIdx.x >> 6, lane = threadIdx.x & 63;
  const int l16 = lane & 15, quad = lane >> 4;
  const int s = blockIdx.x >> 6;
  const int q0w = (blockIdx.x & 63) * 64;
  const int head = w;

  float kmax = sqrtf(__uint_as_float(bounds[head])) * 1.0005f;

  short8 bq[4];
  floatx4 cb[4];                 // C operand = -bound per q-frag
#pragma unroll
  for (int qf = 0; qf < 4; qf++) {
    bq[qf] = *(const short8*)(q + (size_t)(head * NPOS + q0w + qf * 16 + l16) * DH + quad * 8);
    float qn2 = 0.f;
#pragma unroll
    for (int j = 0; j < 8; j++) { float f = bf2f((u16)bq[qf][j]); qn2 += f * f; }
    qn2 += __shfl_xor(qn2, 16);
    qn2 += __shfl_xor(qn2, 32);
    float nb = -sqrtf(qn2) * kmax;
    cb[qf][0] = nb; cb[qf][1] = nb; cb[qf][2] = nb; cb[qf][3] = nb;
  }

  floatx4 o0[4], o1[4], ol[4];
#pragma unroll
  for (int qf = 0; qf < 4; qf++) {
    o0[qf] = (floatx4){0,0,0,0}; o1[qf] = (floatx4){0,0,0,0}; ol[qf] = (floatx4){0,0,0,0};
  }
  short8 ones;
#pragma unroll
  for (int j = 0; j < 8; j++) ones[j] = (short)0x3F80;   // bf16 1.0

  // lane base for permuted K rows: ko0 = (l16>>2)*8 + (l16&3); subtile imm offsets
  // ko[s2]*DH - ko0*DH = {0, 128, 1024, 1152} elems.
  const int ko0 = (l16 >> 2) * 8 + (l16 & 3);
  const u16* kbase  = k + (size_t)head * NPOS * DH + (size_t)(s * KSPAN + ko0) * DH + quad * 8;
  const u16* vbase0 = v + (size_t)(head * DH + l16) * NPOS + s * KSPAN + quad * 8;
  const u16* vbase1 = vbase0 + (size_t)16 * NPOS;

  short8 akA[4], avA[4], akB[4], avB[4];

  auto loadT = [&](short8* ak, short8* av, int it) {
    const u16* kb = kbase + it * 2048;               // 64 keys * 32 d per tile
    ak[0] = *(const short8*)(kb);
    ak[1] = *(const short8*)(kb + 128);
    ak[2] = *(const short8*)(kb + 1024);
    ak[3] = *(const short8*)(kb + 1152);
    const u16* v0 = vbase0 + it * 64;
    const u16* v1 = vbase1 + it * 64;
    av[0] = *(const short8*)(v0);
    av[1] = *(const short8*)(v1);
    av[2] = *(const short8*)(v0 + 32);
    av[3] = *(const short8*)(v1 + 32);
  };

  auto compute = [&](const short8* ak, const short8* av) {
#pragma unroll
    for (int qf = 0; qf < 4; qf++) {
      floatx4 c0 = __builtin_amdgcn_mfma_f32_16x16x32_bf16(ak[0], bq[qf], cb[qf], 0, 0, 0);
      floatx4 c1 = __builtin_amdgcn_mfma_f32_16x16x32_bf16(ak[1], bq[qf], cb[qf], 0, 0, 0);
      floatx4 c2 = __builtin_amdgcn_mfma_f32_16x16x32_bf16(ak[2], bq[qf], cb[qf], 0, 0, 0);
      floatx4 c3 = __builtin_amdgcn_mfma_f32_16x16x32_bf16(ak[3], bq[qf], cb[qf], 0, 0, 0);
      {
        float p0 = __builtin_amdgcn_exp2f(c0[0]), p1 = __builtin_amdgcn_exp2f(c0[1]);
        float p2 = __builtin_amdgcn_exp2f(c0[2]), p3 = __builtin_amdgcn_exp2f(c0[3]);
        float p4 = __builtin_amdgcn_exp2f(c1[0]), p5 = __builtin_amdgcn_exp2f(c1[1]);
        float p6 = __builtin_amdgcn_exp2f(c1[2]), p7 = __builtin_amdgcn_exp2f(c1[3]);
        uint4 uu = make_uint4(pack2bf_fast(p0, p1), pack2bf_fast(p2, p3),
                              pack2bf_fast(p4, p5), pack2bf_fast(p6, p7));
        short8 pa = *(short8*)&uu;
        o0[qf] = __builtin_amdgcn_mfma_f32_16x16x32_bf16(pa, av[0], o0[qf], 0, 0, 0);
        o1[qf] = __builtin_amdgcn_mfma_f32_16x16x32_bf16(pa, av[1], o1[qf], 0, 0, 0);
        ol[qf] = __builtin_amdgcn_mfma_f32_16x16x32_bf16(pa, ones,  ol[qf], 0, 0, 0);
      }
      {
        float p0 = __builtin_amdgcn_exp2f(c2[0]), p1 = __builtin_amdgcn_exp2f(c2[1]);
        float p2 = __builtin_amdgcn_exp2f(c2[2]), p3 = __builtin_amdgcn_exp2f(c2[3]);
        float p4 = __builtin_amdgcn_exp2f(c3[0]), p5 = __builtin_amdgcn_exp2f(c3[1]);
        float p6 = __builtin_amdgcn_exp2f(c3[2]), p7 = __builtin_amdgcn_exp2f(c3[3]);
        uint4 uu = make_uint4(pack2bf_fast(p0, p1), pack2bf_fast(p2, p3),
                              pack2bf_fast(p4, p5), pack2bf_fast(p6, p7));
        short8 pa = *(short8*)&uu;
        o0[qf] = __builtin_amdgcn_mfma_f32_16x16x32_bf16(pa, av[2], o0[qf], 0, 0, 0);
        o1[qf] = __builtin_amdgcn_mfma_f32_16x16x32_bf16(pa, av[3], o1[qf], 0, 0, 0);
        ol[qf] = __builtin_amdgcn_mfma_f32_16x16x32_bf16(pa, ones,  ol[qf], 0, 0, 0);
      }
    }
  };

  loadT(akA, avA, 0);
#pragma unroll
  for (int it = 0; it < NTILE; it++) {
    if ((it & 1) == 0) {
      if (it + 1 < NTILE) loadT(akB, avB, it + 1);
      compute(akA, avA);
    } else {
      if (it + 1 < NTILE) loadT(akA, avA, it + 1);
      compute(akB, avB);
    }
  }

  u32*   op = Opair + (size_t)(s * NHEAD + head) * NPOS * 16;
  float* lp = lpart + (size_t)(s * NHEAD + head) * NPOS;
#pragma unroll
  for (int qf = 0; qf < 4; qf++) {
#pragma unroll
    for (int r = 0; r < 4; r++) {
      int qq = q0w + qf * 16 + quad * 4 + r;
      op[(size_t)qq * 16 + l16] = pack2bf(o0[qf][r], o1[qf][r]);
      if (l16 == 0) lp[qq] = ol[qf][r];
    }
  }
}

// ---------------- proj GEMM: LDS-deduped 8-way split combine ----------------
__global__ __launch_bounds__(512) void proj_k(const u32* __restrict__ Opair,
                                              const float* __restrict__ lpart,
                                              const u16* __restrict__ wp,
                                              const float* __restrict__ pb,
                                              const float* __restrict__ x,
                                              float* __restrict__ out) {
  const int t = threadIdx.x;
  const int w = t >> 6, lane = t & 63;
  const int l16 = lane & 15, quad = lane >> 4;
  const int n0 = blockIdx.x * 16;
  const floatx4 zero = {0.f, 0.f, 0.f, 0.f};
  __shared__ __align__(16) u16 at_lds[16][136];

  {
    const int n = t & 15, ci = t >> 4;               // ci 0..31
    const int c0 = ci * 4, head = c0 >> 5, off = c0 & 31;
    const int half = off >> 4, j0 = off & 15;
    float acc[4] = {0.f, 0.f, 0.f, 0.f};
    float l = 0.f;
#pragma unroll
    for (int s2 = 0; s2 < NSPLIT; s2++) {
      const u32* pp = Opair + ((size_t)(s2 * NHEAD + head) * NPOS + n0 + n) * 16 + j0;
      uint4 u = *(const uint4*)pp;
      u32 uu[4] = {u.x, u.y, u.z, u.w};
#pragma unroll
      for (int j = 0; j < 4; j++)
        acc[j] += half ? __uint_as_float(uu[j] & 0xffff0000u)
                       : __uint_as_float(uu[j] << 16);
      l += lpart[(size_t)(s2 * NHEAD + head) * NPOS + n0 + n];
    }
    float inv = 1.0f / fmaxf(l, 1e-30f);
    *(uint2*)&at_lds[n][c0] = make_uint2(pack2bf(acc[0]*inv, acc[1]*inv),
                                         pack2bf(acc[2]*inv, acc[3]*inv));
  }
  __syncthreads();

  short8 bfr[4];
#pragma unroll
  for (int kk = 0; kk < 4; kk++)
    bfr[kk] = *(const short8*)&at_lds[l16][kk * 32 + quad * 8];
  const int ow = w * 16;
  floatx4 a0 = zero;
  const u16* ap = wp + (size_t)(ow + l16) * NCH + quad * 8;
#pragma unroll
  for (int kk = 0; kk < 4; kk++)
    a0 = __builtin_amdgcn_mfma_f32_16x16x32_bf16(*(const short8*)(ap + kk*32), bfr[kk], a0, 0,0,0);
  const int n = n0 + l16;
#pragma unroll
  for (int r = 0; r < 4; r++) {
    int o = ow + quad * 4 + r;
    size_t idx = (size_t)o * NPOS + n;
    out[idx] = a0[r] + pb[o] + x[idx];
  }
}

extern "C" void kernel_launch(void* const* d_in, const int* in_sizes, int n_in,
                              void* d_out, int out_size, void* d_ws, size_t ws_size,
                              hipStream_t stream) {
  const float* x   = (const float*)d_in[0];
  const float* gnw = (const float*)d_in[1];
  const float* gnb = (const float*)d_in[2];
  const float* qw  = (const float*)d_in[3];
  const float* qb  = (const float*)d_in[4];
  const float* kw  = (const float*)d_in[5];
  const float* kb  = (const float*)d_in[6];
  const float* vw  = (const float*)d_in[7];
  const float* vb  = (const float*)d_in[8];
  const float* pw  = (const float*)d_in[9];
  const float* pb  = (const float*)d_in[10];
  float* out = (float*)d_out;

  char* wsb = (char*)d_ws;
  float2* partials = (float2*)wsb;                       // 4 KB
  u32*    bounds   = (u32*)(wsb + 4096);                 // 16 B
  u16* wqb = (u16*)(wsb + 8192);                         // 4 x 32 KB
  u16* wkb = wqb + 16384;
  u16* wvb = wkb + 16384;
  u16* wpb = wvb + 16384;
  u16* qbuf = wpb + 16384;                               // [h][n][d] 1 MB
  u16* kbuf = qbuf + NTOT;                               // [h][n][d] 1 MB
  u16* vbuf = kbuf + NTOT;                               // [h][d][n] 1 MB
  u32* Opair = (u32*)(vbuf + NTOT);                      // [8][h][q][16] u32 = 8 MB
  float* lpart = (float*)(Opair + (size_t)NSPLIT * NHEAD * NPOS * 16);  // 512 KB

  gn_prep_k<<<512, 256, 0, stream>>>(x, partials, bounds, qw, kw, vw, pw,
                                     wqb, wkb, wvb, wpb);
  qkv_k<<<256, 768, 0, stream>>>(x, gnw, gnb, partials, wqb, wkb, wvb,
                                 qb, kb, vb, qbuf, kbuf, vbuf, bounds);
  attn_k<<<64 * NSPLIT, 256, 0, stream>>>(qbuf, kbuf, vbuf, bounds, Opair, lpart);
  proj_k<<<256, 512, 0, stream>>>(Opair, lpart, wpb, pb, x, out);
}

// Round 8
// 117.091 us; speedup vs baseline: 1.2427x; 1.0060x over previous
//
#include <hip/hip_runtime.h>

#define NPOS 4096
#define NCH  128
#define NTOT (NPOS * NCH)   // 524288
#define NHEAD 4
#define DH    32
#define NSPLIT 8
#define KSPAN (NPOS / NSPLIT)   // 512 keys per split
#define NTILE (KSPAN / 64)      // 8 tiles per split

typedef __attribute__((ext_vector_type(8))) short short8;   // 8 bf16
typedef __attribute__((ext_vector_type(4))) float floatx4;  // MFMA acc
typedef unsigned short u16;
typedef unsigned int   u32;

__device__ __forceinline__ u16 f2bf(float f) {              // RNE
  u32 u = __float_as_uint(f);
  u += 0x7fffu + ((u >> 16) & 1u);
  return (u16)(u >> 16);
}
__device__ __forceinline__ u32 pack2bf(float a, float b) {
  return (u32)f2bf(a) | ((u32)f2bf(b) << 16);
}
__device__ __forceinline__ u32 pack2bf_fast(float a, float b) {  // round-half-up
  return ((__float_as_uint(a) + 0x8000u) >> 16) |
         ((__float_as_uint(b) + 0x8000u) & 0xffff0000u);
}
__device__ __forceinline__ float bf2f(u16 h) {
  return __uint_as_float(((u32)h) << 16);
}

// ---------------- GN partial sums (512 blocks) + weight bf16 prep ----------------
__global__ __launch_bounds__(256) void gn_prep_k(const float* __restrict__ x,
                                                 float2* __restrict__ partials,
                                                 u32* __restrict__ bounds,
                                                 const float* __restrict__ qw, const float* __restrict__ kw,
                                                 const float* __restrict__ vw, const float* __restrict__ pw,
                                                 u16* __restrict__ wq, u16* __restrict__ wk,
                                                 u16* __restrict__ wv, u16* __restrict__ wp) {
  int i = blockIdx.x * 256 + threadIdx.x;           // 0..131071 float4
  int w = threadIdx.x >> 6, lane = threadIdx.x & 63;
  float4 a = ((const float4*)x)[i];
  float s  = a.x + a.y + a.z + a.w;
  float sq = a.x*a.x + a.y*a.y + a.z*a.z + a.w*a.w;
#pragma unroll
  for (int m = 1; m < 64; m <<= 1) {
    s  += __shfl_xor(s, m);
    sq += __shfl_xor(sq, m);
  }
  __shared__ float red[8];
  if (lane == 0) { red[w] = s; red[4 + w] = sq; }
  __syncthreads();
  if (threadIdx.x == 0)
    partials[blockIdx.x] = make_float2(red[0]+red[1]+red[2]+red[3],
                                       red[4]+red[5]+red[6]+red[7]);
  if (blockIdx.x == 0 && threadIdx.x < 4) bounds[threadIdx.x] = 0;
  if (blockIdx.x < 16) {
    int t = blockIdx.x * 256 + threadIdx.x;         // 0..4095 float4 idx into 128x128
    const float sc = 0.17677669529663687f * 1.4426950408889634f;  // d^-0.5 * log2e
    float4 v = ((const float4*)qw)[t];
    ((uint2*)wq)[t] = make_uint2(pack2bf(v.x*sc, v.y*sc), pack2bf(v.z*sc, v.w*sc));
    v = ((const float4*)kw)[t];
    ((uint2*)wk)[t] = make_uint2(pack2bf(v.x, v.y), pack2bf(v.z, v.w));
    v = ((const float4*)vw)[t];
    ((uint2*)wv)[t] = make_uint2(pack2bf(v.x, v.y), pack2bf(v.z, v.w));
    v = ((const float4*)pw)[t];
    ((uint2*)wp)[t] = make_uint2(pack2bf(v.x, v.y), pack2bf(v.z, v.w));
  }
}

// ---------------- fused GN + QKV GEMM: 12 waves = 3 mats x 4 heads ----------------
__global__ __launch_bounds__(768) void qkv_k(const float* __restrict__ x,
    const float* __restrict__ gw, const float* __restrict__ gb,
    const float2* __restrict__ partials,
    const u16* __restrict__ wq, const u16* __restrict__ wk, const u16* __restrict__ wv,
    const float* __restrict__ qb, const float* __restrict__ kb, const float* __restrict__ vb,
    u16* __restrict__ q, u16* __restrict__ k, u16* __restrict__ v, u32* __restrict__ bounds) {
  const int t = threadIdx.x;
  const int w = t >> 6, lane = t & 63;
  const int l16 = lane & 15, quad = lane >> 4;
  const int n0 = blockIdx.x * 16;
  const floatx4 zero = {0.f, 0.f, 0.f, 0.f};

  __shared__ float red[16];
  __shared__ float2 swb[128];
  __shared__ __align__(16) u16 hs[16][136];

  if (t < 512) {
    float2 p = partials[t];
    float s = p.x, sq = p.y;
#pragma unroll
    for (int m = 1; m < 64; m <<= 1) {
      s  += __shfl_xor(s, m);
      sq += __shfl_xor(sq, m);
    }
    if (lane == 0) { red[w] = s; red[8 + w] = sq; }
  }
  __syncthreads();
  float mean = (red[0]+red[1]+red[2]+red[3]+red[4]+red[5]+red[6]+red[7]) * (1.0f / NTOT);
  float var  = (red[8]+red[9]+red[10]+red[11]+red[12]+red[13]+red[14]+red[15]) * (1.0f / NTOT)
               - mean * mean;
  float rstd = rsqrtf(var + 1e-5f);
  if (t < 128) {
    float swv = gw[t] * rstd;
    swb[t] = make_float2(swv, gb[t] - mean * swv);
  }
  __syncthreads();
  if (t < 512) {
    int c = t >> 2, seg = t & 3;
    float4 xv = *(const float4*)(x + (size_t)c * NPOS + n0 + seg * 4);
    float2 sb = swb[c];
    int nl = seg * 4;
    hs[nl + 0][c] = f2bf(xv.x * sb.x + sb.y);
    hs[nl + 1][c] = f2bf(xv.y * sb.x + sb.y);
    hs[nl + 2][c] = f2bf(xv.z * sb.x + sb.y);
    hs[nl + 3][c] = f2bf(xv.w * sb.x + sb.y);
  }
  __syncthreads();

  short8 bfr[4];
#pragma unroll
  for (int kk = 0; kk < 4; kk++)
    bfr[kk] = *(const short8*)&hs[l16][kk * 32 + quad * 8];

  const int mat = w >> 2, head = w & 3, ow = head * 32;
  const u16* wm = (mat == 0) ? wq : (mat == 1) ? wk : wv;
  floatx4 a0 = zero, a1 = zero;
  const u16* ap = wm + (size_t)(ow + l16) * NCH + quad * 8;
#pragma unroll
  for (int kk = 0; kk < 4; kk++) {
    a0 = __builtin_amdgcn_mfma_f32_16x16x32_bf16(*(const short8*)(ap + kk*32),          bfr[kk], a0, 0,0,0);
    a1 = __builtin_amdgcn_mfma_f32_16x16x32_bf16(*(const short8*)(ap + 16*NCH + kk*32), bfr[kk], a1, 0,0,0);
  }
  const int n = n0 + l16;
  if (mat == 0) {
    const float sc = 0.17677669529663687f * 1.4426950408889634f;
    u16* qp = q + (size_t)(head * NPOS + n) * DH;
#pragma unroll
    for (int ss = 0; ss < 2; ss++) {
      floatx4 acc = ss ? a1 : a0;
      int od = ss * 16 + quad * 4;
      float r0 = acc[0] + qb[ow+od+0]*sc, r1 = acc[1] + qb[ow+od+1]*sc;
      float r2 = acc[2] + qb[ow+od+2]*sc, r3 = acc[3] + qb[ow+od+3]*sc;
      *(uint2*)(qp + od) = make_uint2(pack2bf(r0, r1), pack2bf(r2, r3));
    }
  } else if (mat == 1) {
    float sumsq = 0.f;
    u16* kp = k + (size_t)(head * NPOS + n) * DH;
#pragma unroll
    for (int ss = 0; ss < 2; ss++) {
      floatx4 acc = ss ? a1 : a0;
      int od = ss * 16 + quad * 4;
      float r0 = acc[0] + kb[ow+od+0], r1 = acc[1] + kb[ow+od+1];
      float r2 = acc[2] + kb[ow+od+2], r3 = acc[3] + kb[ow+od+3];
      sumsq += r0*r0 + r1*r1 + r2*r2 + r3*r3;
      *(uint2*)(kp + od) = make_uint2(pack2bf(r0, r1), pack2bf(r2, r3));
    }
    sumsq += __shfl_xor(sumsq, 16);
    sumsq += __shfl_xor(sumsq, 32);
#pragma unroll
    for (int m = 1; m < 16; m <<= 1) sumsq = fmaxf(sumsq, __shfl_xor(sumsq, m));
    if (lane == 0) atomicMax(&bounds[head], __float_as_uint(sumsq));
  } else {
    u16* vp = v + (size_t)(head * DH) * NPOS + n;
#pragma unroll
    for (int ss = 0; ss < 2; ss++) {
      floatx4 acc = ss ? a1 : a0;
      int od = ss * 16 + quad * 4;
#pragma unroll
      for (int r = 0; r < 4; r++)
        vp[(size_t)(od + r) * NPOS] = f2bf(acc[r] + vb[ow + od + r]);
    }
  }
}

// ---------------- flash attention: Q=64/wave, same-head blocks, XCD-pinned splits ----
// grid 512 x 256: split = b&7 (== XCD of block), i = b>>3: head = i&3, qblock = i>>2.
// All 4 waves of a block share (head, split) -> identical K/V streams (L1/L2 reuse);
// wave w covers queries qblock*256 + w*64 .. +64.
// K A-frag permutation pi makes each lane's S^T C-regs its PV A-frag (LDS-free).
// -bound folded into the QK MFMA C operand.
__global__ __launch_bounds__(256, 2) void attn_k(const u16* __restrict__ q, const u16* __restrict__ k,
                                                 const u16* __restrict__ v, const u32* __restrict__ bounds,
                                                 u32* __restrict__ Opair, float* __restrict__ lpart) {
  const int w = threadIdx.x >> 6, lane = threadIdx.x & 63;
  const int l16 = lane & 15, quad = lane >> 4;
  const int s    = blockIdx.x & 7;                 // split, pinned per XCD
  const int i    = blockIdx.x >> 3;
  const int head = i & 3;
  const int q0w  = (i >> 2) * 256 + w * 64;        // this wave's 64 queries

  float kmax = sqrtf(__uint_as_float(bounds[head])) * 1.0005f;

  short8 bq[4];
  floatx4 cb[4];                 // C operand = -bound per q-frag
#pragma unroll
  for (int qf = 0; qf < 4; qf++) {
    bq[qf] = *(const short8*)(q + (size_t)(head * NPOS + q0w + qf * 16 + l16) * DH + quad * 8);
    float qn2 = 0.f;
#pragma unroll
    for (int j = 0; j < 8; j++) { float f = bf2f((u16)bq[qf][j]); qn2 += f * f; }
    qn2 += __shfl_xor(qn2, 16);
    qn2 += __shfl_xor(qn2, 32);
    float nb = -sqrtf(qn2) * kmax;
    cb[qf][0] = nb; cb[qf][1] = nb; cb[qf][2] = nb; cb[qf][3] = nb;
  }

  floatx4 o0[4], o1[4], ol[4];
#pragma unroll
  for (int qf = 0; qf < 4; qf++) {
    o0[qf] = (floatx4){0,0,0,0}; o1[qf] = (floatx4){0,0,0,0}; ol[qf] = (floatx4){0,0,0,0};
  }
  short8 ones;
#pragma unroll
  for (int j = 0; j < 8; j++) ones[j] = (short)0x3F80;   // bf16 1.0

  // permuted K rows: ko0 = (l16>>2)*8 + (l16&3); subtile offsets {0,128,1024,1152} elems
  const int ko0 = (l16 >> 2) * 8 + (l16 & 3);
  const u16* kbase  = k + (size_t)head * NPOS * DH + (size_t)(s * KSPAN + ko0) * DH + quad * 8;
  const u16* vbase0 = v + (size_t)(head * DH + l16) * NPOS + s * KSPAN + quad * 8;
  const u16* vbase1 = vbase0 + (size_t)16 * NPOS;

  short8 akA[4], avA[4], akB[4], avB[4];

  auto loadT = [&](short8* ak, short8* av, int it) {
    const u16* kb = kbase + it * 2048;               // 64 keys * 32 d per tile
    ak[0] = *(const short8*)(kb);
    ak[1] = *(const short8*)(kb + 128);
    ak[2] = *(const short8*)(kb + 1024);
    ak[3] = *(const short8*)(kb + 1152);
    const u16* v0 = vbase0 + it * 64;
    const u16* v1 = vbase1 + it * 64;
    av[0] = *(const short8*)(v0);
    av[1] = *(const short8*)(v1);
    av[2] = *(const short8*)(v0 + 32);
    av[3] = *(const short8*)(v1 + 32);
  };

  auto compute = [&](const short8* ak, const short8* av) {
#pragma unroll
    for (int qf = 0; qf < 4; qf++) {
      floatx4 c0 = __builtin_amdgcn_mfma_f32_16x16x32_bf16(ak[0], bq[qf], cb[qf], 0, 0, 0);
      floatx4 c1 = __builtin_amdgcn_mfma_f32_16x16x32_bf16(ak[1], bq[qf], cb[qf], 0, 0, 0);
      floatx4 c2 = __builtin_amdgcn_mfma_f32_16x16x32_bf16(ak[2], bq[qf], cb[qf], 0, 0, 0);
      floatx4 c3 = __builtin_amdgcn_mfma_f32_16x16x32_bf16(ak[3], bq[qf], cb[qf], 0, 0, 0);
      {
        float p0 = __builtin_amdgcn_exp2f(c0[0]), p1 = __builtin_amdgcn_exp2f(c0[1]);
        float p2 = __builtin_amdgcn_exp2f(c0[2]), p3 = __builtin_amdgcn_exp2f(c0[3]);
        float p4 = __builtin_amdgcn_exp2f(c1[0]), p5 = __builtin_amdgcn_exp2f(c1[1]);
        float p6 = __builtin_amdgcn_exp2f(c1[2]), p7 = __builtin_amdgcn_exp2f(c1[3]);
        uint4 uu = make_uint4(pack2bf_fast(p0, p1), pack2bf_fast(p2, p3),
                              pack2bf_fast(p4, p5), pack2bf_fast(p6, p7));
        short8 pa = *(short8*)&uu;
        o0[qf] = __builtin_amdgcn_mfma_f32_16x16x32_bf16(pa, av[0], o0[qf], 0, 0, 0);
        o1[qf] = __builtin_amdgcn_mfma_f32_16x16x32_bf16(pa, av[1], o1[qf], 0, 0, 0);
        ol[qf] = __builtin_amdgcn_mfma_f32_16x16x32_bf16(pa, ones,  ol[qf], 0, 0, 0);
      }
      {
        float p0 = __builtin_amdgcn_exp2f(c2[0]), p1 = __builtin_amdgcn_exp2f(c2[1]);
        float p2 = __builtin_amdgcn_exp2f(c2[2]), p3 = __builtin_amdgcn_exp2f(c2[3]);
        float p4 = __builtin_amdgcn_exp2f(c3[0]), p5 = __builtin_amdgcn_exp2f(c3[1]);
        float p6 = __builtin_amdgcn_exp2f(c3[2]), p7 = __builtin_amdgcn_exp2f(c3[3]);
        uint4 uu = make_uint4(pack2bf_fast(p0, p1), pack2bf_fast(p2, p3),
                              pack2bf_fast(p4, p5), pack2bf_fast(p6, p7));
        short8 pa = *(short8*)&uu;
        o0[qf] = __builtin_amdgcn_mfma_f32_16x16x32_bf16(pa, av[2], o0[qf], 0, 0, 0);
        o1[qf] = __builtin_amdgcn_mfma_f32_16x16x32_bf16(pa, av[3], o1[qf], 0, 0, 0);
        ol[qf] = __builtin_amdgcn_mfma_f32_16x16x32_bf16(pa, ones,  ol[qf], 0, 0, 0);
      }
    }
  };

  loadT(akA, avA, 0);
#pragma unroll
  for (int it = 0; it < NTILE; it++) {
    if ((it & 1) == 0) {
      if (it + 1 < NTILE) loadT(akB, avB, it + 1);
      compute(akA, avA);
    } else {
      if (it + 1 < NTILE) loadT(akA, avA, it + 1);
      compute(akB, avB);
    }
  }

  u32*   op = Opair + (size_t)(s * NHEAD + head) * NPOS * 16;
  float* lp = lpart + (size_t)(s * NHEAD + head) * NPOS;
#pragma unroll
  for (int qf = 0; qf < 4; qf++) {
#pragma unroll
    for (int r = 0; r < 4; r++) {
      int qq = q0w + qf * 16 + quad * 4 + r;
      op[(size_t)qq * 16 + l16] = pack2bf(o0[qf][r], o1[qf][r]);
      if (l16 == 0) lp[qq] = ol[qf][r];
    }
  }
}

// ---------------- proj GEMM: LDS-deduped 8-way split combine ----------------
__global__ __launch_bounds__(512) void proj_k(const u32* __restrict__ Opair,
                                              const float* __restrict__ lpart,
                                              const u16* __restrict__ wp,
                                              const float* __restrict__ pb,
                                              const float* __restrict__ x,
                                              float* __restrict__ out) {
  const int t = threadIdx.x;
  const int w = t >> 6, lane = t & 63;
  const int l16 = lane & 15, quad = lane >> 4;
  const int n0 = blockIdx.x * 16;
  const floatx4 zero = {0.f, 0.f, 0.f, 0.f};
  __shared__ __align__(16) u16 at_lds[16][136];

  {
    const int n = t & 15, ci = t >> 4;               // ci 0..31
    const int c0 = ci * 4, head = c0 >> 5, off = c0 & 31;
    const int half = off >> 4, j0 = off & 15;
    float acc[4] = {0.f, 0.f, 0.f, 0.f};
    float l = 0.f;
#pragma unroll
    for (int s2 = 0; s2 < NSPLIT; s2++) {
      const u32* pp = Opair + ((size_t)(s2 * NHEAD + head) * NPOS + n0 + n) * 16 + j0;
      uint4 u = *(const uint4*)pp;
      u32 uu[4] = {u.x, u.y, u.z, u.w};
#pragma unroll
      for (int j = 0; j < 4; j++)
        acc[j] += half ? __uint_as_float(uu[j] & 0xffff0000u)
                       : __uint_as_float(uu[j] << 16);
      l += lpart[(size_t)(s2 * NHEAD + head) * NPOS + n0 + n];
    }
    float inv = 1.0f / fmaxf(l, 1e-30f);
    *(uint2*)&at_lds[n][c0] = make_uint2(pack2bf(acc[0]*inv, acc[1]*inv),
                                         pack2bf(acc[2]*inv, acc[3]*inv));
  }
  __syncthreads();

  short8 bfr[4];
#pragma unroll
  for (int kk = 0; kk < 4; kk++)
    bfr[kk] = *(const short8*)&at_lds[l16][kk * 32 + quad * 8];
  const int ow = w * 16;
  floatx4 a0 = zero;
  const u16* ap = wp + (size_t)(ow + l16) * NCH + quad * 8;
#pragma unroll
  for (int kk = 0; kk < 4; kk++)
    a0 = __builtin_amdgcn_mfma_f32_16x16x32_bf16(*(const short8*)(ap + kk*32), bfr[kk], a0, 0,0,0);
  const int n = n0 + l16;
#pragma unroll
  for (int r = 0; r < 4; r++) {
    int o = ow + quad * 4 + r;
    size_t idx = (size_t)o * NPOS + n;
    out[idx] = a0[r] + pb[o] + x[idx];
  }
}

extern "C" void kernel_launch(void* const* d_in, const int* in_sizes, int n_in,
                              void* d_out, int out_size, void* d_ws, size_t ws_size,
                              hipStream_t stream) {
  const float* x   = (const float*)d_in[0];
  const float* gnw = (const float*)d_in[1];
  const float* gnb = (const float*)d_in[2];
  const float* qw  = (const float*)d_in[3];
  const float* qb  = (const float*)d_in[4];
  const float* kw  = (const float*)d_in[5];
  const float* kb  = (const float*)d_in[6];
  const float* vw  = (const float*)d_in[7];
  const float* vb  = (const float*)d_in[8];
  const float* pw  = (const float*)d_in[9];
  const float* pb  = (const float*)d_in[10];
  float* out = (float*)d_out;

  char* wsb = (char*)d_ws;
  float2* partials = (float2*)wsb;                       // 4 KB
  u32*    bounds   = (u32*)(wsb + 4096);                 // 16 B
  u16* wqb = (u16*)(wsb + 8192);                         // 4 x 32 KB
  u16* wkb = wqb + 16384;
  u16* wvb = wkb + 16384;
  u16* wpb = wvb + 16384;
  u16* qbuf = wpb + 16384;                               // [h][n][d] 1 MB
  u16* kbuf = qbuf + NTOT;                               // [h][n][d] 1 MB
  u16* vbuf = kbuf + NTOT;                               // [h][d][n] 1 MB
  u32* Opair = (u32*)(vbuf + NTOT);                      // [8][h][q][16] u32 = 8 MB
  float* lpart = (float*)(Opair + (size_t)NSPLIT * NHEAD * NPOS * 16);  // 512 KB

  gn_prep_k<<<512, 256, 0, stream>>>(x, partials, bounds, qw, kw, vw, pw,
                                     wqb, wkb, wvb, wpb);
  qkv_k<<<256, 768, 0, stream>>>(x, gnw, gnb, partials, wqb, wkb, wvb,
                                 qb, kb, vb, qbuf, kbuf, vbuf, bounds);
  attn_k<<<64 * NSPLIT, 256, 0, stream>>>(qbuf, kbuf, vbuf, bounds, Opair, lpart);
  proj_k<<<256, 512, 0, stream>>>(Opair, lpart, wpb, pb, x, out);
}